// Round 6
// baseline (152.749 us; speedup 1.0000x reference)
//
#include <hip/hip_runtime.h>

typedef __bf16 bf16x8 __attribute__((ext_vector_type(8)));
typedef float f32x4 __attribute__((ext_vector_type(4)));
typedef unsigned short ushort8 __attribute__((ext_vector_type(8)));

#define DMODEL 1024
#define HEADS 16
#define DH 64
#define BATCH 2
#define SEQ 2048

__device__ __forceinline__ unsigned short f2bf(float f) {
  unsigned int u = __builtin_bit_cast(unsigned int, f);
  u += 0x7FFFu + ((u >> 16) & 1u);
  return (unsigned short)(u >> 16);
}

// ---------------- fp32 -> bf16 conversion (8 elems/thread) ----------------
__global__ void cvt8(const float* __restrict__ src, unsigned short* __restrict__ dst, int n8) {
  int i = blockIdx.x * 256 + threadIdx.x;
  if (i >= n8) return;
  const float4* s4 = (const float4*)src;
  float4 a = s4[(size_t)i * 2];
  float4 b = s4[(size_t)i * 2 + 1];
  ushort8 o;
  o[0] = f2bf(a.x); o[1] = f2bf(a.y); o[2] = f2bf(a.z); o[3] = f2bf(a.w);
  o[4] = f2bf(b.x); o[5] = f2bf(b.y); o[6] = f2bf(b.z); o[7] = f2bf(b.w);
  *(ushort8*)(dst + (size_t)i * 8) = o;
}

// one launch for all 4 weight matrices (blockIdx.y selects)
__global__ void cvtW(const float* __restrict__ w0, const float* __restrict__ w1,
                     const float* __restrict__ w2, const float* __restrict__ w3,
                     unsigned short* __restrict__ dst) {
  const int by = blockIdx.y;
  const float* src = by == 0 ? w0 : by == 1 ? w1 : by == 2 ? w2 : w3;
  const int i = blockIdx.x * 256 + threadIdx.x;  // 131072 chunks of 8
  const float4* s4 = (const float4*)src;
  float4 a = s4[(size_t)i * 2];
  float4 b = s4[(size_t)i * 2 + 1];
  ushort8 o;
  o[0] = f2bf(a.x); o[1] = f2bf(a.y); o[2] = f2bf(a.z); o[3] = f2bf(a.w);
  o[4] = f2bf(b.x); o[5] = f2bf(b.y); o[6] = f2bf(b.z); o[7] = f2bf(b.w);
  *(ushort8*)(dst + (size_t)by * 1048576 + (size_t)i * 8) = o;
}

// ---------------- deep-pipelined 256x256 QKV GEMM (T3+T4+T5) --------------
// C[4096,3072] = xb[4096,1024] @ wqkv[3072,1024]^T, epilogue scatters to
// qb/kb [bh][s][64] and vtb [bh][64][s] in bf16.
// 512 threads = 8 waves (2M x 4N), per-wave C = 128x64, BK=32.
// Quad-buffered LDS (4 x (A 16KB + B 16KB) = 128 KB), prefetch distance 3
// K-tiles. Per K-tile 2 phases; counted vmcnt(8) once per K-tile (never 0).
// Raw s_barrier (no implicit vmcnt drain). Chunk-XOR LDS swizzle.
__global__ __launch_bounds__(512, 2) void gemm_qkv(
    const unsigned short* __restrict__ A, const unsigned short* __restrict__ Bm,
    unsigned short* __restrict__ qb, unsigned short* __restrict__ kb,
    unsigned short* __restrict__ vt)
{
  __shared__ alignas(16) unsigned short sBuf[4][2][8192];  // [buf][A/B][256*32]
  const int K = 1024, NKT = 32;
  const int tid = threadIdx.x;
  const int lane = tid & 63, wave = tid >> 6;
  const int wm = wave >> 2, wn = wave & 3;       // 2 x 4 wave grid
  const int l15 = lane & 15, lg = lane >> 4;

  // XCD-chunked bijective swizzle: 192 blocks, 24 per XCD
  const int id = blockIdx.x;
  const int nid = (id & 7) * 24 + (id >> 3);
  const int bx = nid % 12, by = nid / 12;
  const int row0 = by * 256, col0 = bx * 256;

  // per-thread staging constants: flat f -> row = f>>2, lds chunk = f&3,
  // source chunk = (f&3) ^ (row&3)  (involution; read applies same XOR)
  const int fA0 = tid, fA1 = 512 + tid;
  const int rA0 = fA0 >> 2, rA1 = fA1 >> 2;
  const int cA0 = (fA0 & 3) ^ (rA0 & 3), cA1 = (fA1 & 3) ^ (rA1 & 3);
  const size_t aS0 = (size_t)(row0 + rA0) * K + cA0 * 8;
  const size_t aS1 = (size_t)(row0 + rA1) * K + cA1 * 8;
  const size_t bS0 = (size_t)(col0 + rA0) * K + cA0 * 8;
  const size_t bS1 = (size_t)(col0 + rA1) * K + cA1 * 8;

  auto stageA = [&](int st, int bb) {
    __builtin_amdgcn_global_load_lds(
        (const __attribute__((address_space(1))) void*)(A + st * 32 + aS0),
        (__attribute__((address_space(3))) void*)(&sBuf[bb][0][fA0 * 8]), 16, 0, 0);
    __builtin_amdgcn_global_load_lds(
        (const __attribute__((address_space(1))) void*)(A + st * 32 + aS1),
        (__attribute__((address_space(3))) void*)(&sBuf[bb][0][fA1 * 8]), 16, 0, 0);
  };
  auto stageB = [&](int st, int bb) {
    __builtin_amdgcn_global_load_lds(
        (const __attribute__((address_space(1))) void*)(Bm + st * 32 + bS0),
        (__attribute__((address_space(3))) void*)(&sBuf[bb][1][fA0 * 8]), 16, 0, 0);
    __builtin_amdgcn_global_load_lds(
        (const __attribute__((address_space(1))) void*)(Bm + st * 32 + bS1),
        (__attribute__((address_space(3))) void*)(&sBuf[bb][1][fA1 * 8]), 16, 0, 0);
  };

  f32x4 acc[8][4] = {};

  // prologue: stage K-tiles 0,1,2 (12 loads/thread), wait tile 0 (vmcnt 8)
  stageA(0, 0); stageB(0, 0);
  stageA(1, 1); stageB(1, 1);
  stageA(2, 2); stageB(2, 2);
  asm volatile("s_waitcnt vmcnt(8)" ::: "memory");
  __builtin_amdgcn_sched_barrier(0);
  __builtin_amdgcn_s_barrier();

  for (int kt = 0; kt < NKT; ++kt) {
    const int cb = kt & 3;
    const unsigned short* bufA = &sBuf[cb][0][0];
    const unsigned short* bufB = &sBuf[cb][1][0];
    int st = kt + 3; if (st >= NKT) st -= NKT;   // dummy-stage tail (never read)
    const int sb = (kt + 3) & 3;

    // ---- phase 0: B frags + A rows 0..63 (of this wave's 128) ----
    bf16x8 bfr[4], af[4];
#pragma unroll
    for (int nt = 0; nt < 4; ++nt) {
      const int row = wn * 64 + nt * 16 + l15;
      bfr[nt] = *(const bf16x8*)&bufB[row * 32 + ((lg ^ (row & 3)) << 3)];
    }
#pragma unroll
    for (int mt = 0; mt < 4; ++mt) {
      const int row = wm * 128 + mt * 16 + l15;
      af[mt] = *(const bf16x8*)&bufA[row * 32 + ((lg ^ (row & 3)) << 3)];
    }
    stageA(st, sb);
    __builtin_amdgcn_s_barrier();
    asm volatile("s_waitcnt lgkmcnt(0)" ::: "memory");
    __builtin_amdgcn_sched_barrier(0);
    __builtin_amdgcn_s_setprio(1);
#pragma unroll
    for (int mt = 0; mt < 4; ++mt)
#pragma unroll
      for (int nt = 0; nt < 4; ++nt)
        acc[mt][nt] = __builtin_amdgcn_mfma_f32_16x16x32_bf16(af[mt], bfr[nt], acc[mt][nt], 0, 0, 0);
    __builtin_amdgcn_s_setprio(0);
    __builtin_amdgcn_s_barrier();

    // ---- phase 1: A rows 64..127 ----
#pragma unroll
    for (int mt = 0; mt < 4; ++mt) {
      const int row = wm * 128 + (mt + 4) * 16 + l15;
      af[mt] = *(const bf16x8*)&bufA[row * 32 + ((lg ^ (row & 3)) << 3)];
    }
    stageB(st, sb);
    __builtin_amdgcn_s_barrier();
    asm volatile("s_waitcnt lgkmcnt(0)" ::: "memory");
    __builtin_amdgcn_sched_barrier(0);
    __builtin_amdgcn_s_setprio(1);
#pragma unroll
    for (int mt = 0; mt < 4; ++mt)
#pragma unroll
      for (int nt = 0; nt < 4; ++nt)
        acc[mt + 4][nt] = __builtin_amdgcn_mfma_f32_16x16x32_bf16(af[mt], bfr[nt], acc[mt + 4][nt], 0, 0, 0);
    __builtin_amdgcn_s_setprio(0);
    // counted wait: tiles k+1..k+3 outstanding (12 loads); wait oldest 4 -> k+1 ready
    asm volatile("s_waitcnt vmcnt(8)" ::: "memory");
    __builtin_amdgcn_sched_barrier(0);
    __builtin_amdgcn_s_barrier();
  }

  asm volatile("s_waitcnt vmcnt(0)" ::: "memory");

  // ---- epilogue: scatter to q/k (bf16 [bh][s][64]) and v^T ([bh][64][s])
#pragma unroll
  for (int mt = 0; mt < 8; ++mt) {
#pragma unroll
    for (int nt = 0; nt < 4; ++nt) {
      const int c = col0 + wn * 64 + nt * 16 + l15;
      const int which = c >> 10, c2 = c & 1023;
      const int h = c2 >> 6, d = c2 & 63;
#pragma unroll
      for (int reg = 0; reg < 4; ++reg) {
        const int r = row0 + wm * 128 + mt * 16 + lg * 4 + reg;
        const int b = r >> 11, s = r & 2047;
        const unsigned short bv = f2bf(acc[mt][nt][reg]);
        if (which == 0)
          qb[(((size_t)(b * HEADS + h)) * SEQ + s) * DH + d] = bv;
        else if (which == 1)
          kb[(((size_t)(b * HEADS + h)) * SEQ + s) * DH + d] = bv;
        else
          vt[(((size_t)(b * HEADS + h)) * DH + d) * SEQ + s] = bv;
      }
    }
  }
}

// ---------------- GEMM: C[M,N] = A[M,K] @ B[N,K]^T (fp32 out) -------------
// (m97-style 128x128, used for the output projection)
__global__ __launch_bounds__(256) void gemm_bt(
    const unsigned short* __restrict__ A, const unsigned short* __restrict__ Bm,
    int K, float* __restrict__ fout)
{
  __shared__ alignas(16) unsigned short sA[128 * 32];
  __shared__ alignas(16) unsigned short sB[128 * 32];
  const int tid = threadIdx.x;
  const int lane = tid & 63, wave = tid >> 6;
  const int wm = wave >> 1, wn = wave & 1;
  const int l15 = lane & 15, lg = lane >> 4;
  const int row0 = blockIdx.y * 128, col0 = blockIdx.x * 128;

  f32x4 acc[4][4] = {};

  for (int k0 = 0; k0 < K; k0 += 32) {
#pragma unroll
    for (int i = 0; i < 2; ++i) {
      int flat = i * 256 + tid;
      int r = flat >> 2, cs = (flat & 3) * 8;
      __builtin_amdgcn_global_load_lds(
          (const __attribute__((address_space(1))) void*)(A + (size_t)(row0 + r) * K + k0 + cs),
          (__attribute__((address_space(3))) void*)(sA + flat * 8), 16, 0, 0);
      __builtin_amdgcn_global_load_lds(
          (const __attribute__((address_space(1))) void*)(Bm + (size_t)(col0 + r) * K + k0 + cs),
          (__attribute__((address_space(3))) void*)(sB + flat * 8), 16, 0, 0);
    }
    __syncthreads();
    bf16x8 af[4], bfr[4];
#pragma unroll
    for (int m = 0; m < 4; ++m)
      af[m] = *(const bf16x8*)&sA[(wm * 64 + m * 16 + l15) * 32 + lg * 8];
#pragma unroll
    for (int n = 0; n < 4; ++n)
      bfr[n] = *(const bf16x8*)&sB[(wn * 64 + n * 16 + l15) * 32 + lg * 8];
#pragma unroll
    for (int m = 0; m < 4; ++m)
#pragma unroll
      for (int n = 0; n < 4; ++n)
        acc[m][n] = __builtin_amdgcn_mfma_f32_16x16x32_bf16(af[m], bfr[n], acc[m][n], 0, 0, 0);
    __syncthreads();
  }

#pragma unroll
  for (int m = 0; m < 4; ++m)
#pragma unroll
    for (int n = 0; n < 4; ++n) {
      const int c = col0 + wn * 64 + n * 16 + l15;
#pragma unroll
      for (int reg = 0; reg < 4; ++reg) {
        const int r = row0 + wm * 64 + m * 16 + lg * 4 + reg;
        fout[(size_t)r * DMODEL + c] = acc[m][n][reg];
      }
    }
}

// ---------------- causal flash attention (paired q-tiles + team kv-split) --
__global__ __launch_bounds__(512, 4) void attn_fwd(
    const unsigned short* __restrict__ q, const unsigned short* __restrict__ k,
    const unsigned short* __restrict__ vt, unsigned short* __restrict__ attn)
{
  __shared__ alignas(16) unsigned short sK[2][64 * 64];  // [team][kv][d], swizzled
  __shared__ alignas(16) unsigned short sV[2][64 * 64];  // [team][d][kv], swizzled
  __shared__ alignas(16) unsigned short sP[8][16 * 64];  // per-wave, swizzled

  const int tid = threadIdx.x, lane = tid & 63, wave = tid >> 6;
  const int team = wave >> 2, wsub = wave & 3;
  const int l15 = lane & 15, lg = lane >> 4;
  const int bh = blockIdx.y;
  const int j = blockIdx.x;
  const int q0a = j * 64, q0b = (31 - j) * 64;
  const int ntA = j + 1, ntB = 32 - j;

  const unsigned short* qg = q + ((size_t)bh * SEQ) * DH;
  const unsigned short* kg = k + ((size_t)bh * SEQ) * DH;
  const unsigned short* vg = vt + ((size_t)bh * DH) * SEQ;

  bf16x8 qfA[2], qfB[2];
#pragma unroll
  for (int ks = 0; ks < 2; ++ks) {
    qfA[ks] = *(const bf16x8*)(qg + (size_t)(q0a + wsub * 16 + l15) * DH + ks * 32 + lg * 8);
    qfB[ks] = *(const bf16x8*)(qg + (size_t)(q0b + wsub * 16 + l15) * DH + ks * 32 + lg * 8);
  }

  f32x4 O[4] = {};
  float m_r = -1e30f, l_r = 0.f;

  const int srow = tid >> 3;
  const int sc = (tid & 7) ^ (srow & 7);
  const int kOff = srow * DH + sc * 8;
  const int vOff = srow * SEQ + sc * 8;

  auto stage = [&](int u0, int u1, int nt) {
    const int kv0 = u0 * 64;
    const int kv1 = (u1 < nt ? u1 : 0) * 64;
    __builtin_amdgcn_global_load_lds(
        (const __attribute__((address_space(1))) void*)(kg + (size_t)kv0 * DH + kOff),
        (__attribute__((address_space(3))) void*)(&sK[0][tid * 8]), 16, 0, 0);
    __builtin_amdgcn_global_load_lds(
        (const __attribute__((address_space(1))) void*)(vg + (size_t)kv0 + vOff),
        (__attribute__((address_space(3))) void*)(&sV[0][tid * 8]), 16, 0, 0);
    __builtin_amdgcn_global_load_lds(
        (const __attribute__((address_space(1))) void*)(kg + (size_t)kv1 * DH + kOff),
        (__attribute__((address_space(3))) void*)(&sK[1][tid * 8]), 16, 0, 0);
    __builtin_amdgcn_global_load_lds(
        (const __attribute__((address_space(1))) void*)(vg + (size_t)kv1 + vOff),
        (__attribute__((address_space(3))) void*)(&sV[1][tid * 8]), 16, 0, 0);
  };

  const float CSC = 0.18033688011112042f;  // 0.125 * log2(e)
  const float THR = 44.3614195558365f;     // 8 / CSC

  auto tile = [&](const bf16x8 (&qf)[2], int kv0, int qwv) {
    f32x4 st[4] = {};
    const char* sKb = (const char*)&sK[team][0];
    __builtin_amdgcn_s_setprio(1);
#pragma unroll
    for (int kt = 0; kt < 4; ++kt) {
      const int row = kt * 16 + l15;
      const bf16x8 kf0 = *(const bf16x8*)(sKb + row * 128 + ((lg ^ (row & 7)) * 16));
      const bf16x8 kf1 = *(const bf16x8*)(sKb + row * 128 + (((4 + lg) ^ (row & 7)) * 16));
      st[kt] = __builtin_amdgcn_mfma_f32_16x16x32_bf16(kf0, qf[0], st[kt], 0, 0, 0);
      st[kt] = __builtin_amdgcn_mfma_f32_16x16x32_bf16(kf1, qf[1], st[kt], 0, 0, 0);
    }
    __builtin_amdgcn_s_setprio(0);

    const bool needmask = (kv0 + 63 > qwv);
    const int qgl = qwv + l15;
    float mx = -1e30f;
#pragma unroll
    for (int kt = 0; kt < 4; ++kt)
#pragma unroll
      for (int r = 0; r < 4; ++r) {
        float v = st[kt][r];
        if (needmask) {
          const int kv = kv0 + kt * 16 + lg * 4 + r;
          v = (kv <= qgl) ? v : -1e30f;
          st[kt][r] = v;
        }
        mx = fmaxf(mx, v);
      }
    mx = fmaxf(mx, __shfl_xor(mx, 16));
    mx = fmaxf(mx, __shfl_xor(mx, 32));

    if (!__all(mx - m_r <= THR)) {
      const float mn = fmaxf(m_r, mx);
      const float al = exp2f((m_r - mn) * CSC);
      l_r *= al;
      m_r = mn;
#pragma unroll
      for (int r = 0; r < 4; ++r) {
        const float ab = __shfl(al, lg * 4 + r);
#pragma unroll
        for (int dt = 0; dt < 4; ++dt) O[dt][r] *= ab;
      }
    }

    unsigned short* sPw = &sP[wave][0];
    const float nm = -m_r * CSC;
    float ps = 0.f;
#pragma unroll
    for (int kt = 0; kt < 4; ++kt) {
      const float e0 = exp2f(__builtin_fmaf(st[kt][0], CSC, nm));
      const float e1 = exp2f(__builtin_fmaf(st[kt][1], CSC, nm));
      const float e2 = exp2f(__builtin_fmaf(st[kt][2], CSC, nm));
      const float e3 = exp2f(__builtin_fmaf(st[kt][3], CSC, nm));
      ps += (e0 + e1) + (e2 + e3);
      unsigned w0, w1;
      asm("v_cvt_pk_bf16_f32 %0, %1, %2" : "=v"(w0) : "v"(e0), "v"(e1));
      asm("v_cvt_pk_bf16_f32 %0, %1, %2" : "=v"(w1) : "v"(e2), "v"(e3));
      uint2 w; w.x = w0; w.y = w1;
      const int byteoff = l15 * 128 + ((kt * 32 + lg * 8) ^ ((l15 & 7) << 4));
      *(uint2*)((char*)sPw + byteoff) = w;
    }
    ps += __shfl_xor(ps, 16);
    ps += __shfl_xor(ps, 32);
    l_r += ps;

    asm volatile("s_waitcnt lgkmcnt(0)" ::: "memory");
    __builtin_amdgcn_sched_barrier(0);

    const char* sVb = (const char*)&sV[team][0];
    __builtin_amdgcn_s_setprio(1);
#pragma unroll
    for (int ks = 0; ks < 2; ++ks) {
      const bf16x8 pf = *(const bf16x8*)((const char*)sPw +
          (l15 * 128 + ((ks * 64 + lg * 16) ^ ((l15 & 7) << 4))));
#pragma unroll
      for (int dt = 0; dt < 4; ++dt) {
        const int row = dt * 16 + l15;
        const bf16x8 vf = *(const bf16x8*)(sVb + row * 128 + (((ks * 4 + lg) ^ (row & 7)) * 16));
        O[dt] = __builtin_amdgcn_mfma_f32_16x16x32_bf16(pf, vf, O[dt], 0, 0, 0);
      }
    }
    __builtin_amdgcn_s_setprio(0);
  };

  const int b = bh >> 4, h = bh & 15;
  auto writeOut = [&](int q0w) {
    const float inv = 1.0f / l_r;
#pragma unroll
    for (int r = 0; r < 4; ++r) {
      const float iv = __shfl(inv, lg * 4 + r);
      const int s = q0w + wsub * 16 + lg * 4 + r;
#pragma unroll
      for (int dt = 0; dt < 4; ++dt)
        attn[((size_t)(b * SEQ + s)) * DMODEL + h * DH + dt * 16 + l15] =
            f2bf(O[dt][r] * iv);
    }
  };

  auto phase = [&](const bf16x8 (&qf)[2], int q0, int nt) {
    const int qw = q0 + wsub * 16;
    const int nsteps = (nt + 1) >> 1;
    for (int i = 0; i < nsteps; ++i) {
      const int u = 2 * i + team;
      stage(2 * i, 2 * i + 1, nt);
      __syncthreads();
      const int kv0 = u * 64;
      if (u < nt && kv0 <= qw + 15) tile(qf, kv0, qw);
      __syncthreads();
    }
    float* mb = (float*)&sP[0][0];
    if (team == 1) {
      float* bp = mb + wsub * 640;
#pragma unroll
      for (int dt = 0; dt < 2; ++dt)
#pragma unroll
        for (int r = 0; r < 4; ++r) bp[(dt * 4 + r) * 64 + lane] = O[dt][r];
      bp[512 + lane] = m_r;
      bp[576 + lane] = l_r;
    }
    __syncthreads();
    float a0 = 1.f, a1 = 0.f;
    if (team == 0) {
      float* bp = mb + wsub * 640;
      const float m1 = bp[512 + lane], l1 = bp[576 + lane];
      const float ms = fmaxf(m_r, m1);
      a0 = exp2f((m_r - ms) * CSC);
      a1 = exp2f((m1 - ms) * CSC);
      l_r = l_r * a0 + l1 * a1;
      m_r = ms;
#pragma unroll
      for (int r = 0; r < 4; ++r) {
        const float c0 = __shfl(a0, lg * 4 + r), c1 = __shfl(a1, lg * 4 + r);
        O[0][r] = O[0][r] * c0 + bp[r * 64 + lane] * c1;
        O[1][r] = O[1][r] * c0 + bp[(4 + r) * 64 + lane] * c1;
      }
    }
    __syncthreads();
    if (team == 1) {
      float* bp = mb + wsub * 512;
#pragma unroll
      for (int dt = 0; dt < 2; ++dt)
#pragma unroll
        for (int r = 0; r < 4; ++r) bp[(dt * 4 + r) * 64 + lane] = O[dt + 2][r];
    }
    __syncthreads();
    if (team == 0) {
      float* bp = mb + wsub * 512;
#pragma unroll
      for (int r = 0; r < 4; ++r) {
        const float c0 = __shfl(a0, lg * 4 + r), c1 = __shfl(a1, lg * 4 + r);
        O[2][r] = O[2][r] * c0 + bp[r * 64 + lane] * c1;
        O[3][r] = O[3][r] * c0 + bp[(4 + r) * 64 + lane] * c1;
      }
      writeOut(q0);
    }
    __syncthreads();
  };

  phase(qfA, q0a, ntA);
#pragma unroll
  for (int dt = 0; dt < 4; ++dt) O[dt] = f32x4{0.f, 0.f, 0.f, 0.f};
  m_r = -1e30f; l_r = 0.f;
  phase(qfB, q0b, ntB);
}

// ---------------------------------------------------------------------------
extern "C" void kernel_launch(void* const* d_in, const int* in_sizes, int n_in,
                              void* d_out, int out_size, void* d_ws, size_t ws_size,
                              hipStream_t stream) {
  const float* x  = (const float*)d_in[0];
  // d_in[1] = causal mask (tril) — structure known, not read
  const float* Wq = (const float*)d_in[2];
  const float* Wk = (const float*)d_in[3];
  const float* Wv = (const float*)d_in[4];
  const float* Wo = (const float*)d_in[5];
  float* out = (float*)d_out;

  unsigned short* ws = (unsigned short*)d_ws;
  const size_t MEL = (size_t)1024 * 1024;
  unsigned short* xb   = ws;            // 4M elems
  unsigned short* wqkv = xb + 4 * MEL;  // 3M (Wq|Wk|Wv rows)
  unsigned short* wo   = wqkv + 3 * MEL;// 1M
  unsigned short* qb   = wo + MEL;      // 4M  [bh][s][64]
  unsigned short* kb   = qb + 4 * MEL;  // 4M  [bh][s][64]
  unsigned short* vtb  = kb + 4 * MEL;  // 4M  [bh][64][s]
  unsigned short* attn = vtb + 4 * MEL; // 4M  [b*s][1024]

  cvt8<<<2048, 256, 0, stream>>>(x, xb, 524288);
  cvtW<<<dim3(512, 4), 256, 0, stream>>>(Wq, Wk, Wv, Wo, wqkv);

  gemm_qkv<<<192, 512, 0, stream>>>(xb, wqkv, qb, kb, vtb);

  dim3 g2(16, BATCH * HEADS);  // attention: paired q-tiles + team kv-split
  attn_fwd<<<g2, 512, 0, stream>>>(qb, kb, vtb, attn);

  dim3 g3(1024 / 128, 4096 / 128);  // output projection
  gemm_bt<<<g3, 256, 0, stream>>>(attn, wo, DMODEL, out);
}

// Round 7
// 124.375 us; speedup vs baseline: 1.2281x; 1.2281x over previous
//
#include <hip/hip_runtime.h>

typedef __bf16 bf16x8 __attribute__((ext_vector_type(8)));
typedef float f32x4 __attribute__((ext_vector_type(4)));
typedef unsigned short ushort8 __attribute__((ext_vector_type(8)));

#define DMODEL 1024
#define HEADS 16
#define DH 64
#define BATCH 2
#define SEQ 2048

__device__ __forceinline__ unsigned short f2bf(float f) {
  unsigned int u = __builtin_bit_cast(unsigned int, f);
  u += 0x7FFFu + ((u >> 16) & 1u);
  return (unsigned short)(u >> 16);
}

// ---------------- fp32 -> bf16 conversion (8 elems/thread) ----------------
__global__ void cvt8(const float* __restrict__ src, unsigned short* __restrict__ dst, int n8) {
  int i = blockIdx.x * 256 + threadIdx.x;
  if (i >= n8) return;
  const float4* s4 = (const float4*)src;
  float4 a = s4[(size_t)i * 2];
  float4 b = s4[(size_t)i * 2 + 1];
  ushort8 o;
  o[0] = f2bf(a.x); o[1] = f2bf(a.y); o[2] = f2bf(a.z); o[3] = f2bf(a.w);
  o[4] = f2bf(b.x); o[5] = f2bf(b.y); o[6] = f2bf(b.z); o[7] = f2bf(b.w);
  *(ushort8*)(dst + (size_t)i * 8) = o;
}

// one launch for all 4 weight matrices (blockIdx.y selects)
__global__ void cvtW(const float* __restrict__ w0, const float* __restrict__ w1,
                     const float* __restrict__ w2, const float* __restrict__ w3,
                     unsigned short* __restrict__ dst) {
  const int by = blockIdx.y;
  const float* src = by == 0 ? w0 : by == 1 ? w1 : by == 2 ? w2 : w3;
  const int i = blockIdx.x * 256 + threadIdx.x;
  const float4* s4 = (const float4*)src;
  float4 a = s4[(size_t)i * 2];
  float4 b = s4[(size_t)i * 2 + 1];
  ushort8 o;
  o[0] = f2bf(a.x); o[1] = f2bf(a.y); o[2] = f2bf(a.z); o[3] = f2bf(a.w);
  o[4] = f2bf(b.x); o[5] = f2bf(b.y); o[6] = f2bf(b.z); o[7] = f2bf(b.w);
  *(ushort8*)(dst + (size_t)by * 1048576 + (size_t)i * 8) = o;
}

// ---------------- 128x128 GEMM, triple-buffered counted-vmcnt pipeline ----
// C[M,N] = A[M,K=1024] @ B[N,K]^T, bf16 in, f32 acc. 256 threads = 4 waves
// (2x2), per-wave 64x64. LDS 3 x (A 8KB + B 8KB) = 48KB -> 3 blocks/CU.
// Per K-tile: {ds_read frags; issue stage(k+2); 16 MFMA; vmcnt(4); barrier}
// - ONE barrier per tile, loads stay in flight across it (T4 counted vmcnt).
// WAR safety: buffer (k+2)%3 last read at tile k-1; its reads completed
// before that tile's MFMA (lgkmcnt) and its end barrier precedes this stage.
// MODE 0: QKV scatter epilogue (bf16 q/k [bh][s][64], v^T [bh][64][s])
// MODE 1: fp32 row-major out (ldc = DMODEL)
template<int MODE>
__global__ __launch_bounds__(256, 3) void gemm_p3(
    const unsigned short* __restrict__ A, const unsigned short* __restrict__ Bm,
    int NBX,
    unsigned short* __restrict__ qb, unsigned short* __restrict__ kb,
    unsigned short* __restrict__ vt, float* __restrict__ fout)
{
  constexpr int K = 1024, NKT = 32;
  __shared__ alignas(16) unsigned short sBuf[3][2][128 * 32];
  const int tid = threadIdx.x;
  const int lane = tid & 63, wave = tid >> 6;
  const int wm = wave >> 1, wn = wave & 1;
  const int l15 = lane & 15, lg = lane >> 4;

  // bijective XCD swizzle (gridDim.x % 8 == 0 for both call sites)
  const int cpx = (int)gridDim.x >> 3;
  const int id = blockIdx.x;
  const int nid = (id & 7) * cpx + (id >> 3);
  const int bx = nid % NBX, by = nid / NBX;
  const int row0 = by * 128, col0 = bx * 128;

  // staging: flat slot f -> row = f>>2, lds chunk = f&3, src chunk ^(row&3)
  const int f0 = tid, f1 = 256 + tid;
  const int r0 = f0 >> 2, r1 = f1 >> 2;
  const int c0 = (f0 & 3) ^ (r0 & 3), c1 = (f1 & 3) ^ (r1 & 3);
  const size_t aS0 = (size_t)(row0 + r0) * K + c0 * 8;
  const size_t aS1 = (size_t)(row0 + r1) * K + c1 * 8;
  const size_t bS0 = (size_t)(col0 + r0) * K + c0 * 8;
  const size_t bS1 = (size_t)(col0 + r1) * K + c1 * 8;

  auto stage = [&](int st, int bb) {
    __builtin_amdgcn_global_load_lds(
        (const __attribute__((address_space(1))) void*)(A + st * 32 + aS0),
        (__attribute__((address_space(3))) void*)(&sBuf[bb][0][f0 * 8]), 16, 0, 0);
    __builtin_amdgcn_global_load_lds(
        (const __attribute__((address_space(1))) void*)(A + st * 32 + aS1),
        (__attribute__((address_space(3))) void*)(&sBuf[bb][0][f1 * 8]), 16, 0, 0);
    __builtin_amdgcn_global_load_lds(
        (const __attribute__((address_space(1))) void*)(Bm + st * 32 + bS0),
        (__attribute__((address_space(3))) void*)(&sBuf[bb][1][f0 * 8]), 16, 0, 0);
    __builtin_amdgcn_global_load_lds(
        (const __attribute__((address_space(1))) void*)(Bm + st * 32 + bS1),
        (__attribute__((address_space(3))) void*)(&sBuf[bb][1][f1 * 8]), 16, 0, 0);
  };

  f32x4 acc[4][4] = {};

  // prologue: tiles 0,1 staged; wait tile 0 (4 of 8 outstanding)
  stage(0, 0);
  stage(1, 1);
  asm volatile("s_waitcnt vmcnt(4)" ::: "memory");
  __builtin_amdgcn_s_barrier();
  asm volatile("" ::: "memory");

  const int xorc = (lg ^ (l15 & 3)) << 3;  // read-side chunk XOR (row&3 = l15&3)
  int cb = 0;
  for (int kt = 0; kt < NKT; ++kt) {
    const unsigned short* bufA = &sBuf[cb][0][0];
    const unsigned short* bufB = &sBuf[cb][1][0];
    int sb = cb + 2; if (sb >= 3) sb -= 3;

    bf16x8 af[4], bfr[4];
#pragma unroll
    for (int m = 0; m < 4; ++m)
      af[m] = *(const bf16x8*)&bufA[(wm * 64 + m * 16 + l15) * 32 + xorc];
#pragma unroll
    for (int n = 0; n < 4; ++n)
      bfr[n] = *(const bf16x8*)&bufB[(wn * 64 + n * 16 + l15) * 32 + xorc];

    if (kt < NKT - 2) stage(kt + 2, sb);  // overlap loads with MFMA

    __builtin_amdgcn_s_setprio(1);
#pragma unroll
    for (int m = 0; m < 4; ++m)
#pragma unroll
      for (int n = 0; n < 4; ++n)
        acc[m][n] = __builtin_amdgcn_mfma_f32_16x16x32_bf16(af[m], bfr[n], acc[m][n], 0, 0, 0);
    __builtin_amdgcn_s_setprio(0);

    if (kt < NKT - 2) {
      asm volatile("s_waitcnt vmcnt(4)" ::: "memory");  // tile k+1 ready
    } else {
      asm volatile("s_waitcnt vmcnt(0)" ::: "memory");  // tail drain
    }
    __builtin_amdgcn_s_barrier();
    asm volatile("" ::: "memory");  // no cross-iteration LDS-read CSE
    cb = cb + 1; if (cb >= 3) cb -= 3;
  }

  // ---- epilogue. C/D layout: col = lane&15, row = (lane>>4)*4 + reg [m89]
#pragma unroll
  for (int m = 0; m < 4; ++m) {
#pragma unroll
    for (int n = 0; n < 4; ++n) {
      const int c = col0 + wn * 64 + n * 16 + l15;
#pragma unroll
      for (int reg = 0; reg < 4; ++reg) {
        const int r = row0 + wm * 64 + m * 16 + lg * 4 + reg;
        const float v = acc[m][n][reg];
        if (MODE == 0) {
          const int which = c >> 10, c2 = c & 1023;
          const int h = c2 >> 6, d = c2 & 63;
          const int b = r >> 11, s = r & 2047;
          const unsigned short bv = f2bf(v);
          if (which == 0)
            qb[(((size_t)(b * HEADS + h)) * SEQ + s) * DH + d] = bv;
          else if (which == 1)
            kb[(((size_t)(b * HEADS + h)) * SEQ + s) * DH + d] = bv;
          else
            vt[(((size_t)(b * HEADS + h)) * DH + d) * SEQ + s] = bv;
        } else {
          fout[(size_t)r * DMODEL + c] = v;
        }
      }
    }
  }
}

// ---------------- causal flash attention (paired q-tiles + team kv-split) --
__global__ __launch_bounds__(512, 4) void attn_fwd(
    const unsigned short* __restrict__ q, const unsigned short* __restrict__ k,
    const unsigned short* __restrict__ vt, unsigned short* __restrict__ attn)
{
  __shared__ alignas(16) unsigned short sK[2][64 * 64];  // [team][kv][d], swizzled
  __shared__ alignas(16) unsigned short sV[2][64 * 64];  // [team][d][kv], swizzled
  __shared__ alignas(16) unsigned short sP[8][16 * 64];  // per-wave, swizzled

  const int tid = threadIdx.x, lane = tid & 63, wave = tid >> 6;
  const int team = wave >> 2, wsub = wave & 3;
  const int l15 = lane & 15, lg = lane >> 4;
  const int bh = blockIdx.y;
  const int j = blockIdx.x;
  const int q0a = j * 64, q0b = (31 - j) * 64;
  const int ntA = j + 1, ntB = 32 - j;

  const unsigned short* qg = q + ((size_t)bh * SEQ) * DH;
  const unsigned short* kg = k + ((size_t)bh * SEQ) * DH;
  const unsigned short* vg = vt + ((size_t)bh * DH) * SEQ;

  bf16x8 qfA[2], qfB[2];
#pragma unroll
  for (int ks = 0; ks < 2; ++ks) {
    qfA[ks] = *(const bf16x8*)(qg + (size_t)(q0a + wsub * 16 + l15) * DH + ks * 32 + lg * 8);
    qfB[ks] = *(const bf16x8*)(qg + (size_t)(q0b + wsub * 16 + l15) * DH + ks * 32 + lg * 8);
  }

  f32x4 O[4] = {};
  float m_r = -1e30f, l_r = 0.f;

  const int srow = tid >> 3;
  const int sc = (tid & 7) ^ (srow & 7);
  const int kOff = srow * DH + sc * 8;
  const int vOff = srow * SEQ + sc * 8;

  auto stage = [&](int u0, int u1, int nt) {
    const int kv0 = u0 * 64;
    const int kv1 = (u1 < nt ? u1 : 0) * 64;
    __builtin_amdgcn_global_load_lds(
        (const __attribute__((address_space(1))) void*)(kg + (size_t)kv0 * DH + kOff),
        (__attribute__((address_space(3))) void*)(&sK[0][tid * 8]), 16, 0, 0);
    __builtin_amdgcn_global_load_lds(
        (const __attribute__((address_space(1))) void*)(vg + (size_t)kv0 + vOff),
        (__attribute__((address_space(3))) void*)(&sV[0][tid * 8]), 16, 0, 0);
    __builtin_amdgcn_global_load_lds(
        (const __attribute__((address_space(1))) void*)(kg + (size_t)kv1 * DH + kOff),
        (__attribute__((address_space(3))) void*)(&sK[1][tid * 8]), 16, 0, 0);
    __builtin_amdgcn_global_load_lds(
        (const __attribute__((address_space(1))) void*)(vg + (size_t)kv1 + vOff),
        (__attribute__((address_space(3))) void*)(&sV[1][tid * 8]), 16, 0, 0);
  };

  const float CSC = 0.18033688011112042f;  // 0.125 * log2(e)
  const float THR = 44.3614195558365f;     // 8 / CSC

  auto tile = [&](const bf16x8 (&qf)[2], int kv0, int qwv) {
    f32x4 st[4] = {};
    const char* sKb = (const char*)&sK[team][0];
    __builtin_amdgcn_s_setprio(1);
#pragma unroll
    for (int kt = 0; kt < 4; ++kt) {
      const int row = kt * 16 + l15;
      const bf16x8 kf0 = *(const bf16x8*)(sKb + row * 128 + ((lg ^ (row & 7)) * 16));
      const bf16x8 kf1 = *(const bf16x8*)(sKb + row * 128 + (((4 + lg) ^ (row & 7)) * 16));
      st[kt] = __builtin_amdgcn_mfma_f32_16x16x32_bf16(kf0, qf[0], st[kt], 0, 0, 0);
      st[kt] = __builtin_amdgcn_mfma_f32_16x16x32_bf16(kf1, qf[1], st[kt], 0, 0, 0);
    }
    __builtin_amdgcn_s_setprio(0);

    const bool needmask = (kv0 + 63 > qwv);
    const int qgl = qwv + l15;
    float mx = -1e30f;
#pragma unroll
    for (int kt = 0; kt < 4; ++kt)
#pragma unroll
      for (int r = 0; r < 4; ++r) {
        float v = st[kt][r];
        if (needmask) {
          const int kv = kv0 + kt * 16 + lg * 4 + r;
          v = (kv <= qgl) ? v : -1e30f;
          st[kt][r] = v;
        }
        mx = fmaxf(mx, v);
      }
    mx = fmaxf(mx, __shfl_xor(mx, 16));
    mx = fmaxf(mx, __shfl_xor(mx, 32));

    if (!__all(mx - m_r <= THR)) {
      const float mn = fmaxf(m_r, mx);
      const float al = exp2f((m_r - mn) * CSC);
      l_r *= al;
      m_r = mn;
#pragma unroll
      for (int r = 0; r < 4; ++r) {
        const float ab = __shfl(al, lg * 4 + r);
#pragma unroll
        for (int dt = 0; dt < 4; ++dt) O[dt][r] *= ab;
      }
    }

    unsigned short* sPw = &sP[wave][0];
    const float nm = -m_r * CSC;
    float ps = 0.f;
#pragma unroll
    for (int kt = 0; kt < 4; ++kt) {
      const float e0 = exp2f(__builtin_fmaf(st[kt][0], CSC, nm));
      const float e1 = exp2f(__builtin_fmaf(st[kt][1], CSC, nm));
      const float e2 = exp2f(__builtin_fmaf(st[kt][2], CSC, nm));
      const float e3 = exp2f(__builtin_fmaf(st[kt][3], CSC, nm));
      ps += (e0 + e1) + (e2 + e3);
      unsigned w0, w1;
      asm("v_cvt_pk_bf16_f32 %0, %1, %2" : "=v"(w0) : "v"(e0), "v"(e1));
      asm("v_cvt_pk_bf16_f32 %0, %1, %2" : "=v"(w1) : "v"(e2), "v"(e3));
      uint2 w; w.x = w0; w.y = w1;
      const int byteoff = l15 * 128 + ((kt * 32 + lg * 8) ^ ((l15 & 7) << 4));
      *(uint2*)((char*)sPw + byteoff) = w;
    }
    ps += __shfl_xor(ps, 16);
    ps += __shfl_xor(ps, 32);
    l_r += ps;

    asm volatile("s_waitcnt lgkmcnt(0)" ::: "memory");
    __builtin_amdgcn_sched_barrier(0);

    const char* sVb = (const char*)&sV[team][0];
    __builtin_amdgcn_s_setprio(1);
#pragma unroll
    for (int ks = 0; ks < 2; ++ks) {
      const bf16x8 pf = *(const bf16x8*)((const char*)sPw +
          (l15 * 128 + ((ks * 64 + lg * 16) ^ ((l15 & 7) << 4))));
#pragma unroll
      for (int dt = 0; dt < 4; ++dt) {
        const int row = dt * 16 + l15;
        const bf16x8 vf = *(const bf16x8*)(sVb + row * 128 + (((ks * 4 + lg) ^ (row & 7)) * 16));
        O[dt] = __builtin_amdgcn_mfma_f32_16x16x32_bf16(pf, vf, O[dt], 0, 0, 0);
      }
    }
    __builtin_amdgcn_s_setprio(0);
  };

  const int b = bh >> 4, h = bh & 15;
  auto writeOut = [&](int q0w) {
    const float inv = 1.0f / l_r;
#pragma unroll
    for (int r = 0; r < 4; ++r) {
      const float iv = __shfl(inv, lg * 4 + r);
      const int s = q0w + wsub * 16 + lg * 4 + r;
#pragma unroll
      for (int dt = 0; dt < 4; ++dt)
        attn[((size_t)(b * SEQ + s)) * DMODEL + h * DH + dt * 16 + l15] =
            f2bf(O[dt][r] * iv);
    }
  };

  auto phase = [&](const bf16x8 (&qf)[2], int q0, int nt) {
    const int qw = q0 + wsub * 16;
    const int nsteps = (nt + 1) >> 1;
    for (int i = 0; i < nsteps; ++i) {
      const int u = 2 * i + team;
      stage(2 * i, 2 * i + 1, nt);
      __syncthreads();
      const int kv0 = u * 64;
      if (u < nt && kv0 <= qw + 15) tile(qf, kv0, qw);
      __syncthreads();
    }
    float* mb = (float*)&sP[0][0];
    if (team == 1) {
      float* bp = mb + wsub * 640;
#pragma unroll
      for (int dt = 0; dt < 2; ++dt)
#pragma unroll
        for (int r = 0; r < 4; ++r) bp[(dt * 4 + r) * 64 + lane] = O[dt][r];
      bp[512 + lane] = m_r;
      bp[576 + lane] = l_r;
    }
    __syncthreads();
    float a0 = 1.f, a1 = 0.f;
    if (team == 0) {
      float* bp = mb + wsub * 640;
      const float m1 = bp[512 + lane], l1 = bp[576 + lane];
      const float ms = fmaxf(m_r, m1);
      a0 = exp2f((m_r - ms) * CSC);
      a1 = exp2f((m1 - ms) * CSC);
      l_r = l_r * a0 + l1 * a1;
      m_r = ms;
#pragma unroll
      for (int r = 0; r < 4; ++r) {
        const float c0 = __shfl(a0, lg * 4 + r), c1 = __shfl(a1, lg * 4 + r);
        O[0][r] = O[0][r] * c0 + bp[r * 64 + lane] * c1;
        O[1][r] = O[1][r] * c0 + bp[(4 + r) * 64 + lane] * c1;
      }
    }
    __syncthreads();
    if (team == 1) {
      float* bp = mb + wsub * 512;
#pragma unroll
      for (int dt = 0; dt < 2; ++dt)
#pragma unroll
        for (int r = 0; r < 4; ++r) bp[(dt * 4 + r) * 64 + lane] = O[dt + 2][r];
    }
    __syncthreads();
    if (team == 0) {
      float* bp = mb + wsub * 512;
#pragma unroll
      for (int r = 0; r < 4; ++r) {
        const float c0 = __shfl(a0, lg * 4 + r), c1 = __shfl(a1, lg * 4 + r);
        O[2][r] = O[2][r] * c0 + bp[r * 64 + lane] * c1;
        O[3][r] = O[3][r] * c0 + bp[(4 + r) * 64 + lane] * c1;
      }
      writeOut(q0);
    }
    __syncthreads();
  };

  phase(qfA, q0a, ntA);
#pragma unroll
  for (int dt = 0; dt < 4; ++dt) O[dt] = f32x4{0.f, 0.f, 0.f, 0.f};
  m_r = -1e30f; l_r = 0.f;
  phase(qfB, q0b, ntB);
}

// ---------------------------------------------------------------------------
extern "C" void kernel_launch(void* const* d_in, const int* in_sizes, int n_in,
                              void* d_out, int out_size, void* d_ws, size_t ws_size,
                              hipStream_t stream) {
  const float* x  = (const float*)d_in[0];
  // d_in[1] = causal mask (tril) — structure known, not read
  const float* Wq = (const float*)d_in[2];
  const float* Wk = (const float*)d_in[3];
  const float* Wv = (const float*)d_in[4];
  const float* Wo = (const float*)d_in[5];
  float* out = (float*)d_out;

  unsigned short* ws = (unsigned short*)d_ws;
  const size_t MEL = (size_t)1024 * 1024;
  unsigned short* xb   = ws;            // 4M elems
  unsigned short* wqkv = xb + 4 * MEL;  // 3M (Wq|Wk|Wv rows)
  unsigned short* wo   = wqkv + 3 * MEL;// 1M
  unsigned short* qb   = wo + MEL;      // 4M  [bh][s][64]
  unsigned short* kb   = qb + 4 * MEL;  // 4M  [bh][s][64]
  unsigned short* vtb  = kb + 4 * MEL;  // 4M  [bh][64][s]
  unsigned short* attn = vtb + 4 * MEL; // 4M  [b*s][1024]

  cvt8<<<2048, 256, 0, stream>>>(x, xb, 524288);
  cvtW<<<dim3(512, 4), 256, 0, stream>>>(Wq, Wk, Wv, Wo, wqkv);

  // QKV projection: 24 x 32 = 768 blocks (3/CU resident, uniform)
  gemm_p3<0><<<768, 256, 0, stream>>>(xb, wqkv, 24, qb, kb, vtb, nullptr);

  dim3 g2(16, BATCH * HEADS);  // attention: paired q-tiles + team kv-split
  attn_fwd<<<g2, 512, 0, stream>>>(qb, kb, vtb, attn);

  // output projection: 8 x 32 = 256 blocks
  gemm_p3<1><<<256, 256, 0, stream>>>(attn, wo, 8, nullptr, nullptr, nullptr, out);
}

// Round 8
// 124.316 us; speedup vs baseline: 1.2287x; 1.0005x over previous
//
#include <hip/hip_runtime.h>

typedef __bf16 bf16x8 __attribute__((ext_vector_type(8)));
typedef float f32x4 __attribute__((ext_vector_type(4)));
typedef unsigned short ushort8 __attribute__((ext_vector_type(8)));

#define DMODEL 1024
#define HEADS 16
#define DH 64
#define BATCH 2
#define SEQ 2048

__device__ __forceinline__ unsigned short f2bf(float f) {
  unsigned int u = __builtin_bit_cast(unsigned int, f);
  u += 0x7FFFu + ((u >> 16) & 1u);
  return (unsigned short)(u >> 16);
}

// ---------------- fp32 -> bf16 conversion (8 elems/thread) ----------------
__global__ void cvt8(const float* __restrict__ src, unsigned short* __restrict__ dst, int n8) {
  int i = blockIdx.x * 256 + threadIdx.x;
  if (i >= n8) return;
  const float4* s4 = (const float4*)src;
  float4 a = s4[(size_t)i * 2];
  float4 b = s4[(size_t)i * 2 + 1];
  ushort8 o;
  o[0] = f2bf(a.x); o[1] = f2bf(a.y); o[2] = f2bf(a.z); o[3] = f2bf(a.w);
  o[4] = f2bf(b.x); o[5] = f2bf(b.y); o[6] = f2bf(b.z); o[7] = f2bf(b.w);
  *(ushort8*)(dst + (size_t)i * 8) = o;
}

// one launch for all 4 weight matrices (blockIdx.y selects)
__global__ void cvtW(const float* __restrict__ w0, const float* __restrict__ w1,
                     const float* __restrict__ w2, const float* __restrict__ w3,
                     unsigned short* __restrict__ dst) {
  const int by = blockIdx.y;
  const float* src = by == 0 ? w0 : by == 1 ? w1 : by == 2 ? w2 : w3;
  const int i = blockIdx.x * 256 + threadIdx.x;
  const float4* s4 = (const float4*)src;
  float4 a = s4[(size_t)i * 2];
  float4 b = s4[(size_t)i * 2 + 1];
  ushort8 o;
  o[0] = f2bf(a.x); o[1] = f2bf(a.y); o[2] = f2bf(a.z); o[3] = f2bf(a.w);
  o[4] = f2bf(b.x); o[5] = f2bf(b.y); o[6] = f2bf(b.z); o[7] = f2bf(b.w);
  *(ushort8*)(dst + (size_t)by * 1048576 + (size_t)i * 8) = o;
}

// ---------------- 128x128 GEMM, triple-buffered counted-vmcnt pipeline ----
template<int MODE>
__global__ __launch_bounds__(256, 3) void gemm_p3(
    const unsigned short* __restrict__ A, const unsigned short* __restrict__ Bm,
    int NBX,
    unsigned short* __restrict__ qb, unsigned short* __restrict__ kb,
    unsigned short* __restrict__ vt, float* __restrict__ fout)
{
  constexpr int K = 1024, NKT = 32;
  __shared__ alignas(16) unsigned short sBuf[3][2][128 * 32];
  const int tid = threadIdx.x;
  const int lane = tid & 63, wave = tid >> 6;
  const int wm = wave >> 1, wn = wave & 1;
  const int l15 = lane & 15, lg = lane >> 4;

  const int cpx = (int)gridDim.x >> 3;
  const int id = blockIdx.x;
  const int nid = (id & 7) * cpx + (id >> 3);
  const int bx = nid % NBX, by = nid / NBX;
  const int row0 = by * 128, col0 = bx * 128;

  const int f0 = tid, f1 = 256 + tid;
  const int r0 = f0 >> 2, r1 = f1 >> 2;
  const int c0 = (f0 & 3) ^ (r0 & 3), c1 = (f1 & 3) ^ (r1 & 3);
  const size_t aS0 = (size_t)(row0 + r0) * K + c0 * 8;
  const size_t aS1 = (size_t)(row0 + r1) * K + c1 * 8;
  const size_t bS0 = (size_t)(col0 + r0) * K + c0 * 8;
  const size_t bS1 = (size_t)(col0 + r1) * K + c1 * 8;

  auto stage = [&](int st, int bb) {
    __builtin_amdgcn_global_load_lds(
        (const __attribute__((address_space(1))) void*)(A + st * 32 + aS0),
        (__attribute__((address_space(3))) void*)(&sBuf[bb][0][f0 * 8]), 16, 0, 0);
    __builtin_amdgcn_global_load_lds(
        (const __attribute__((address_space(1))) void*)(A + st * 32 + aS1),
        (__attribute__((address_space(3))) void*)(&sBuf[bb][0][f1 * 8]), 16, 0, 0);
    __builtin_amdgcn_global_load_lds(
        (const __attribute__((address_space(1))) void*)(Bm + st * 32 + bS0),
        (__attribute__((address_space(3))) void*)(&sBuf[bb][1][f0 * 8]), 16, 0, 0);
    __builtin_amdgcn_global_load_lds(
        (const __attribute__((address_space(1))) void*)(Bm + st * 32 + bS1),
        (__attribute__((address_space(3))) void*)(&sBuf[bb][1][f1 * 8]), 16, 0, 0);
  };

  f32x4 acc[4][4] = {};

  stage(0, 0);
  stage(1, 1);
  asm volatile("s_waitcnt vmcnt(4)" ::: "memory");
  __builtin_amdgcn_s_barrier();
  asm volatile("" ::: "memory");

  const int xorc = (lg ^ (l15 & 3)) << 3;
  int cb = 0;
  for (int kt = 0; kt < NKT; ++kt) {
    const unsigned short* bufA = &sBuf[cb][0][0];
    const unsigned short* bufB = &sBuf[cb][1][0];
    int sb = cb + 2; if (sb >= 3) sb -= 3;

    bf16x8 af[4], bfr[4];
#pragma unroll
    for (int m = 0; m < 4; ++m)
      af[m] = *(const bf16x8*)&bufA[(wm * 64 + m * 16 + l15) * 32 + xorc];
#pragma unroll
    for (int n = 0; n < 4; ++n)
      bfr[n] = *(const bf16x8*)&bufB[(wn * 64 + n * 16 + l15) * 32 + xorc];

    if (kt < NKT - 2) stage(kt + 2, sb);

    __builtin_amdgcn_s_setprio(1);
#pragma unroll
    for (int m = 0; m < 4; ++m)
#pragma unroll
      for (int n = 0; n < 4; ++n)
        acc[m][n] = __builtin_amdgcn_mfma_f32_16x16x32_bf16(af[m], bfr[n], acc[m][n], 0, 0, 0);
    __builtin_amdgcn_s_setprio(0);

    if (kt < NKT - 2) {
      asm volatile("s_waitcnt vmcnt(4)" ::: "memory");
    } else {
      asm volatile("s_waitcnt vmcnt(0)" ::: "memory");
    }
    __builtin_amdgcn_s_barrier();
    asm volatile("" ::: "memory");
    cb = cb + 1; if (cb >= 3) cb -= 3;
  }

#pragma unroll
  for (int m = 0; m < 4; ++m) {
#pragma unroll
    for (int n = 0; n < 4; ++n) {
      const int c = col0 + wn * 64 + n * 16 + l15;
#pragma unroll
      for (int reg = 0; reg < 4; ++reg) {
        const int r = row0 + wm * 64 + m * 16 + lg * 4 + reg;
        const float v = acc[m][n][reg];
        if (MODE == 0) {
          const int which = c >> 10, c2 = c & 1023;
          const int h = c2 >> 6, d = c2 & 63;
          const int b = r >> 11, s = r & 2047;
          const unsigned short bv = f2bf(v);
          if (which == 0)
            qb[(((size_t)(b * HEADS + h)) * SEQ + s) * DH + d] = bv;
          else if (which == 1)
            kb[(((size_t)(b * HEADS + h)) * SEQ + s) * DH + d] = bv;
          else
            vt[(((size_t)(b * HEADS + h)) * DH + d) * SEQ + s] = bv;
        } else {
          fout[(size_t)r * DMODEL + c] = v;
        }
      }
    }
  }
}

// ---------------- causal flash attention ------------------------------------
// Paired q-tiles + team kv-split + DOUBLE-BUFFERED K/V with counted vmcnt.
// grid: (16, B*H), 512 threads = 8 waves = 2 teams x 4 waves.
// Per step: stage(i+1, buf^1) -> vmcnt(4) -> s_barrier -> tile(i, buf)
// -> s_barrier. Loads for step i were issued one iteration earlier and
// hide under step i-1's compute; no vmcnt(0) drain in the loop.
// LDS = 2*16 + 2*16 + 8 = 72 KB -> 2 blocks/CU = 16 waves/CU.
__global__ __launch_bounds__(512, 4) void attn_fwd(
    const unsigned short* __restrict__ q, const unsigned short* __restrict__ k,
    const unsigned short* __restrict__ vt, unsigned short* __restrict__ attn)
{
  __shared__ alignas(16) unsigned short sK[2][2][64 * 64];  // [buf][team][kv][d]
  __shared__ alignas(16) unsigned short sV[2][2][64 * 64];  // [buf][team][d][kv]
  __shared__ alignas(16) unsigned short sP[8][16 * 64];     // per-wave, swizzled

  const int tid = threadIdx.x, lane = tid & 63, wave = tid >> 6;
  const int team = wave >> 2, wsub = wave & 3;
  const int l15 = lane & 15, lg = lane >> 4;
  const int bh = blockIdx.y;
  const int j = blockIdx.x;
  const int q0a = j * 64, q0b = (31 - j) * 64;
  const int ntA = j + 1, ntB = 32 - j;

  const unsigned short* qg = q + ((size_t)bh * SEQ) * DH;
  const unsigned short* kg = k + ((size_t)bh * SEQ) * DH;
  const unsigned short* vg = vt + ((size_t)bh * DH) * SEQ;

  bf16x8 qfA[2], qfB[2];
#pragma unroll
  for (int ks = 0; ks < 2; ++ks) {
    qfA[ks] = *(const bf16x8*)(qg + (size_t)(q0a + wsub * 16 + l15) * DH + ks * 32 + lg * 8);
    qfB[ks] = *(const bf16x8*)(qg + (size_t)(q0b + wsub * 16 + l15) * DH + ks * 32 + lg * 8);
  }

  f32x4 O[4] = {};
  float m_r = -1e30f, l_r = 0.f;

  // staging offsets: 512 threads fill one team-tile pair (K,V) per team
  const int srow = tid >> 3;
  const int sc = (tid & 7) ^ (srow & 7);
  const int kOff = srow * DH + sc * 8;
  const int vOff = srow * SEQ + sc * 8;

  // stage both teams' kv tiles (u0 even, u1 odd) into buffer bi
  auto stage = [&](int bi, int u0, int u1, int nt) {
    const int kv0 = u0 * 64;
    const int kv1 = (u1 < nt ? u1 : 0) * 64;
    __builtin_amdgcn_global_load_lds(
        (const __attribute__((address_space(1))) void*)(kg + (size_t)kv0 * DH + kOff),
        (__attribute__((address_space(3))) void*)(&sK[bi][0][tid * 8]), 16, 0, 0);
    __builtin_amdgcn_global_load_lds(
        (const __attribute__((address_space(1))) void*)(vg + (size_t)kv0 + vOff),
        (__attribute__((address_space(3))) void*)(&sV[bi][0][tid * 8]), 16, 0, 0);
    __builtin_amdgcn_global_load_lds(
        (const __attribute__((address_space(1))) void*)(kg + (size_t)kv1 * DH + kOff),
        (__attribute__((address_space(3))) void*)(&sK[bi][1][tid * 8]), 16, 0, 0);
    __builtin_amdgcn_global_load_lds(
        (const __attribute__((address_space(1))) void*)(vg + (size_t)kv1 + vOff),
        (__attribute__((address_space(3))) void*)(&sV[bi][1][tid * 8]), 16, 0, 0);
  };

  const float CSC = 0.18033688011112042f;  // 0.125 * log2(e)
  const float THR = 44.3614195558365f;     // 8 / CSC

  auto tile = [&](const bf16x8 (&qf)[2], int kv0, int bi, int qwv) {
    f32x4 st[4] = {};
    const char* sKb = (const char*)&sK[bi][team][0];
    __builtin_amdgcn_s_setprio(1);
#pragma unroll
    for (int kt = 0; kt < 4; ++kt) {
      const int row = kt * 16 + l15;
      const bf16x8 kf0 = *(const bf16x8*)(sKb + row * 128 + ((lg ^ (row & 7)) * 16));
      const bf16x8 kf1 = *(const bf16x8*)(sKb + row * 128 + (((4 + lg) ^ (row & 7)) * 16));
      st[kt] = __builtin_amdgcn_mfma_f32_16x16x32_bf16(kf0, qf[0], st[kt], 0, 0, 0);
      st[kt] = __builtin_amdgcn_mfma_f32_16x16x32_bf16(kf1, qf[1], st[kt], 0, 0, 0);
    }
    __builtin_amdgcn_s_setprio(0);

    const bool needmask = (kv0 + 63 > qwv);
    const int qgl = qwv + l15;
    float mx = -1e30f;
#pragma unroll
    for (int kt = 0; kt < 4; ++kt)
#pragma unroll
      for (int r = 0; r < 4; ++r) {
        float v = st[kt][r];
        if (needmask) {
          const int kv = kv0 + kt * 16 + lg * 4 + r;
          v = (kv <= qgl) ? v : -1e30f;
          st[kt][r] = v;
        }
        mx = fmaxf(mx, v);
      }
    mx = fmaxf(mx, __shfl_xor(mx, 16));
    mx = fmaxf(mx, __shfl_xor(mx, 32));

    if (!__all(mx - m_r <= THR)) {
      const float mn = fmaxf(m_r, mx);
      const float al = exp2f((m_r - mn) * CSC);
      l_r *= al;
      m_r = mn;
#pragma unroll
      for (int r = 0; r < 4; ++r) {
        const float ab = __shfl(al, lg * 4 + r);
#pragma unroll
        for (int dt = 0; dt < 4; ++dt) O[dt][r] *= ab;
      }
    }

    unsigned short* sPw = &sP[wave][0];
    const float nm = -m_r * CSC;
    float ps = 0.f;
#pragma unroll
    for (int kt = 0; kt < 4; ++kt) {
      const float e0 = exp2f(__builtin_fmaf(st[kt][0], CSC, nm));
      const float e1 = exp2f(__builtin_fmaf(st[kt][1], CSC, nm));
      const float e2 = exp2f(__builtin_fmaf(st[kt][2], CSC, nm));
      const float e3 = exp2f(__builtin_fmaf(st[kt][3], CSC, nm));
      ps += (e0 + e1) + (e2 + e3);
      unsigned w0, w1;
      asm("v_cvt_pk_bf16_f32 %0, %1, %2" : "=v"(w0) : "v"(e0), "v"(e1));
      asm("v_cvt_pk_bf16_f32 %0, %1, %2" : "=v"(w1) : "v"(e2), "v"(e3));
      uint2 w; w.x = w0; w.y = w1;
      const int byteoff = l15 * 128 + ((kt * 32 + lg * 8) ^ ((l15 & 7) << 4));
      *(uint2*)((char*)sPw + byteoff) = w;
    }
    ps += __shfl_xor(ps, 16);
    ps += __shfl_xor(ps, 32);
    l_r += ps;

    asm volatile("s_waitcnt lgkmcnt(0)" ::: "memory");
    __builtin_amdgcn_sched_barrier(0);

    const char* sVb = (const char*)&sV[bi][team][0];
    __builtin_amdgcn_s_setprio(1);
#pragma unroll
    for (int ks = 0; ks < 2; ++ks) {
      const bf16x8 pf = *(const bf16x8*)((const char*)sPw +
          (l15 * 128 + ((ks * 64 + lg * 16) ^ ((l15 & 7) << 4))));
#pragma unroll
      for (int dt = 0; dt < 4; ++dt) {
        const int row = dt * 16 + l15;
        const bf16x8 vf = *(const bf16x8*)(sVb + row * 128 + (((ks * 4 + lg) ^ (row & 7)) * 16));
        O[dt] = __builtin_amdgcn_mfma_f32_16x16x32_bf16(pf, vf, O[dt], 0, 0, 0);
      }
    }
    __builtin_amdgcn_s_setprio(0);
  };

  const int b = bh >> 4, h = bh & 15;
  auto writeOut = [&](int q0w) {
    const float inv = 1.0f / l_r;
#pragma unroll
    for (int r = 0; r < 4; ++r) {
      const float iv = __shfl(inv, lg * 4 + r);
      const int s = q0w + wsub * 16 + lg * 4 + r;
#pragma unroll
      for (int dt = 0; dt < 4; ++dt)
        attn[((size_t)(b * SEQ + s)) * DMODEL + h * DH + dt * 16 + l15] =
            f2bf(O[dt][r] * iv);
    }
  };

  auto phase = [&](const bf16x8 (&qf)[2], int q0, int nt) {
    const int qw = q0 + wsub * 16;
    const int nsteps = (nt + 1) >> 1;
    stage(0, 0, 1, nt);  // prologue (exposed once per phase)
    for (int i = 0; i < nsteps; ++i) {
      const bool pf = (i + 1 < nsteps);
      if (pf) stage((i + 1) & 1, 2 * (i + 1), 2 * (i + 1) + 1, nt);
      if (pf) { asm volatile("s_waitcnt vmcnt(4)" ::: "memory"); }
      else    { asm volatile("s_waitcnt vmcnt(0)" ::: "memory"); }
      __builtin_amdgcn_s_barrier();
      asm volatile("" ::: "memory");
      const int u = 2 * i + team;
      const int kv0 = u * 64;
      if (u < nt && kv0 <= qw + 15) tile(qf, kv0, i & 1, qw);
      __builtin_amdgcn_s_barrier();
      asm volatile("" ::: "memory");
    }
    // ---- team merge (flash split-k combine) via sP reinterpreted as f32
    float* mb = (float*)&sP[0][0];
    if (team == 1) {
      float* bp = mb + wsub * 640;
#pragma unroll
      for (int dt = 0; dt < 2; ++dt)
#pragma unroll
        for (int r = 0; r < 4; ++r) bp[(dt * 4 + r) * 64 + lane] = O[dt][r];
      bp[512 + lane] = m_r;
      bp[576 + lane] = l_r;
    }
    __syncthreads();
    float a0 = 1.f, a1 = 0.f;
    if (team == 0) {
      float* bp = mb + wsub * 640;
      const float m1 = bp[512 + lane], l1 = bp[576 + lane];
      const float ms = fmaxf(m_r, m1);
      a0 = exp2f((m_r - ms) * CSC);
      a1 = exp2f((m1 - ms) * CSC);
      l_r = l_r * a0 + l1 * a1;
      m_r = ms;
#pragma unroll
      for (int r = 0; r < 4; ++r) {
        const float c0 = __shfl(a0, lg * 4 + r), c1 = __shfl(a1, lg * 4 + r);
        O[0][r] = O[0][r] * c0 + bp[r * 64 + lane] * c1;
        O[1][r] = O[1][r] * c0 + bp[(4 + r) * 64 + lane] * c1;
      }
    }
    __syncthreads();
    if (team == 1) {
      float* bp = mb + wsub * 512;
#pragma unroll
      for (int dt = 0; dt < 2; ++dt)
#pragma unroll
        for (int r = 0; r < 4; ++r) bp[(dt * 4 + r) * 64 + lane] = O[dt + 2][r];
    }
    __syncthreads();
    if (team == 0) {
      float* bp = mb + wsub * 512;
#pragma unroll
      for (int r = 0; r < 4; ++r) {
        const float c0 = __shfl(a0, lg * 4 + r), c1 = __shfl(a1, lg * 4 + r);
        O[2][r] = O[2][r] * c0 + bp[r * 64 + lane] * c1;
        O[3][r] = O[3][r] * c0 + bp[(4 + r) * 64 + lane] * c1;
      }
      writeOut(q0);
    }
    __syncthreads();
  };

  phase(qfA, q0a, ntA);
#pragma unroll
  for (int dt = 0; dt < 4; ++dt) O[dt] = f32x4{0.f, 0.f, 0.f, 0.f};
  m_r = -1e30f; l_r = 0.f;
  phase(qfB, q0b, ntB);
}

// ---------------------------------------------------------------------------
extern "C" void kernel_launch(void* const* d_in, const int* in_sizes, int n_in,
                              void* d_out, int out_size, void* d_ws, size_t ws_size,
                              hipStream_t stream) {
  const float* x  = (const float*)d_in[0];
  // d_in[1] = causal mask (tril) — structure known, not read
  const float* Wq = (const float*)d_in[2];
  const float* Wk = (const float*)d_in[3];
  const float* Wv = (const float*)d_in[4];
  const float* Wo = (const float*)d_in[5];
  float* out = (float*)d_out;

  unsigned short* ws = (unsigned short*)d_ws;
  const size_t MEL = (size_t)1024 * 1024;
  unsigned short* xb   = ws;            // 4M elems
  unsigned short* wqkv = xb + 4 * MEL;  // 3M (Wq|Wk|Wv rows)
  unsigned short* wo   = wqkv + 3 * MEL;// 1M
  unsigned short* qb   = wo + MEL;      // 4M  [bh][s][64]
  unsigned short* kb   = qb + 4 * MEL;  // 4M  [bh][s][64]
  unsigned short* vtb  = kb + 4 * MEL;  // 4M  [bh][64][s]
  unsigned short* attn = vtb + 4 * MEL; // 4M  [b*s][1024]

  cvt8<<<2048, 256, 0, stream>>>(x, xb, 524288);
  cvtW<<<dim3(512, 4), 256, 0, stream>>>(Wq, Wk, Wv, Wo, wqkv);

  // QKV projection: 24 x 32 = 768 blocks (3/CU resident, uniform)
  gemm_p3<0><<<768, 256, 0, stream>>>(xb, wqkv, 24, qb, kb, vtb, nullptr);

  dim3 g2(16, BATCH * HEADS);  // attention: paired q-tiles + team kv-split
  attn_fwd<<<g2, 512, 0, stream>>>(qb, kb, vtb, attn);

  // output projection: 8 x 32 = 256 blocks
  gemm_p3<1><<<256, 256, 0, stream>>>(attn, wo, 8, nullptr, nullptr, nullptr, out);
}

// Round 10
// 120.198 us; speedup vs baseline: 1.2708x; 1.0343x over previous
//
#include <hip/hip_runtime.h>

typedef __bf16 bf16x8 __attribute__((ext_vector_type(8)));
typedef float f32x4 __attribute__((ext_vector_type(4)));
typedef float f32x16 __attribute__((ext_vector_type(16)));
typedef unsigned short ushort8 __attribute__((ext_vector_type(8)));
typedef unsigned int uint4v __attribute__((ext_vector_type(4)));

#define DMODEL 1024
#define HEADS 16
#define DH 64
#define BATCH 2
#define SEQ 2048

__device__ __forceinline__ unsigned short f2bf(float f) {
  unsigned int u = __builtin_bit_cast(unsigned int, f);
  u += 0x7FFFu + ((u >> 16) & 1u);
  return (unsigned short)(u >> 16);
}

// ---------------- fp32 -> bf16 conversion (8 elems/thread) ----------------
__global__ void cvt8(const float* __restrict__ src, unsigned short* __restrict__ dst, int n8) {
  int i = blockIdx.x * 256 + threadIdx.x;
  if (i >= n8) return;
  const float4* s4 = (const float4*)src;
  float4 a = s4[(size_t)i * 2];
  float4 b = s4[(size_t)i * 2 + 1];
  ushort8 o;
  o[0] = f2bf(a.x); o[1] = f2bf(a.y); o[2] = f2bf(a.z); o[3] = f2bf(a.w);
  o[4] = f2bf(b.x); o[5] = f2bf(b.y); o[6] = f2bf(b.z); o[7] = f2bf(b.w);
  *(ushort8*)(dst + (size_t)i * 8) = o;
}

__global__ void cvtW(const float* __restrict__ w0, const float* __restrict__ w1,
                     const float* __restrict__ w2, const float* __restrict__ w3,
                     unsigned short* __restrict__ dst) {
  const int by = blockIdx.y;
  const float* src = by == 0 ? w0 : by == 1 ? w1 : by == 2 ? w2 : w3;
  const int i = blockIdx.x * 256 + threadIdx.x;
  const float4* s4 = (const float4*)src;
  float4 a = s4[(size_t)i * 2];
  float4 b = s4[(size_t)i * 2 + 1];
  ushort8 o;
  o[0] = f2bf(a.x); o[1] = f2bf(a.y); o[2] = f2bf(a.z); o[3] = f2bf(a.w);
  o[4] = f2bf(b.x); o[5] = f2bf(b.y); o[6] = f2bf(b.z); o[7] = f2bf(b.w);
  *(ushort8*)(dst + (size_t)by * 1048576 + (size_t)i * 8) = o;
}

// ---------------- 128x128 GEMM, triple-buffered counted-vmcnt pipeline ----
template<int MODE>
__global__ __launch_bounds__(256, 3) void gemm_p3(
    const unsigned short* __restrict__ A, const unsigned short* __restrict__ Bm,
    int NBX,
    unsigned short* __restrict__ qb, unsigned short* __restrict__ kb,
    unsigned short* __restrict__ vt, float* __restrict__ fout)
{
  constexpr int K = 1024, NKT = 32;
  __shared__ alignas(16) unsigned short sBuf[3][2][128 * 32];
  const int tid = threadIdx.x;
  const int lane = tid & 63, wave = tid >> 6;
  const int wm = wave >> 1, wn = wave & 1;
  const int l15 = lane & 15, lg = lane >> 4;

  const int cpx = (int)gridDim.x >> 3;
  const int id = blockIdx.x;
  const int nid = (id & 7) * cpx + (id >> 3);
  const int bx = nid % NBX, by = nid / NBX;
  const int row0 = by * 128, col0 = bx * 128;

  const int f0 = tid, f1 = 256 + tid;
  const int r0 = f0 >> 2, r1 = f1 >> 2;
  const int c0 = (f0 & 3) ^ (r0 & 3), c1 = (f1 & 3) ^ (r1 & 3);
  const size_t aS0 = (size_t)(row0 + r0) * K + c0 * 8;
  const size_t aS1 = (size_t)(row0 + r1) * K + c1 * 8;
  const size_t bS0 = (size_t)(col0 + r0) * K + c0 * 8;
  const size_t bS1 = (size_t)(col0 + r1) * K + c1 * 8;

  auto stage = [&](int st, int bb) {
    __builtin_amdgcn_global_load_lds(
        (const __attribute__((address_space(1))) void*)(A + st * 32 + aS0),
        (__attribute__((address_space(3))) void*)(&sBuf[bb][0][f0 * 8]), 16, 0, 0);
    __builtin_amdgcn_global_load_lds(
        (const __attribute__((address_space(1))) void*)(A + st * 32 + aS1),
        (__attribute__((address_space(3))) void*)(&sBuf[bb][0][f1 * 8]), 16, 0, 0);
    __builtin_amdgcn_global_load_lds(
        (const __attribute__((address_space(1))) void*)(Bm + st * 32 + bS0),
        (__attribute__((address_space(3))) void*)(&sBuf[bb][1][f0 * 8]), 16, 0, 0);
    __builtin_amdgcn_global_load_lds(
        (const __attribute__((address_space(1))) void*)(Bm + st * 32 + bS1),
        (__attribute__((address_space(3))) void*)(&sBuf[bb][1][f1 * 8]), 16, 0, 0);
  };

  f32x4 acc[4][4] = {};

  stage(0, 0);
  stage(1, 1);
  asm volatile("s_waitcnt vmcnt(4)" ::: "memory");
  __builtin_amdgcn_s_barrier();
  asm volatile("" ::: "memory");

  const int xorc = (lg ^ (l15 & 3)) << 3;
  int cb = 0;
  for (int kt = 0; kt < NKT; ++kt) {
    const unsigned short* bufA = &sBuf[cb][0][0];
    const unsigned short* bufB = &sBuf[cb][1][0];
    int sb = cb + 2; if (sb >= 3) sb -= 3;

    bf16x8 af[4], bfr[4];
#pragma unroll
    for (int m = 0; m < 4; ++m)
      af[m] = *(const bf16x8*)&bufA[(wm * 64 + m * 16 + l15) * 32 + xorc];
#pragma unroll
    for (int n = 0; n < 4; ++n)
      bfr[n] = *(const bf16x8*)&bufB[(wn * 64 + n * 16 + l15) * 32 + xorc];

    if (kt < NKT - 2) stage(kt + 2, sb);

    __builtin_amdgcn_s_setprio(1);
#pragma unroll
    for (int m = 0; m < 4; ++m)
#pragma unroll
      for (int n = 0; n < 4; ++n)
        acc[m][n] = __builtin_amdgcn_mfma_f32_16x16x32_bf16(af[m], bfr[n], acc[m][n], 0, 0, 0);
    __builtin_amdgcn_s_setprio(0);

    if (kt < NKT - 2) {
      asm volatile("s_waitcnt vmcnt(4)" ::: "memory");
    } else {
      asm volatile("s_waitcnt vmcnt(0)" ::: "memory");
    }
    __builtin_amdgcn_s_barrier();
    asm volatile("" ::: "memory");
    cb = cb + 1; if (cb >= 3) cb -= 3;
  }

#pragma unroll
  for (int m = 0; m < 4; ++m) {
#pragma unroll
    for (int n = 0; n < 4; ++n) {
      const int c = col0 + wn * 64 + n * 16 + l15;
#pragma unroll
      for (int reg = 0; reg < 4; ++reg) {
        const int r = row0 + wm * 64 + m * 16 + lg * 4 + reg;
        const float v = acc[m][n][reg];
        if (MODE == 0) {
          const int which = c >> 10, c2 = c & 1023;
          const int h = c2 >> 6, d = c2 & 63;
          const int b = r >> 11, s = r & 2047;
          const unsigned short bv = f2bf(v);
          if (which == 0)
            qb[(((size_t)(b * HEADS + h)) * SEQ + s) * DH + d] = bv;
          else if (which == 1)
            kb[(((size_t)(b * HEADS + h)) * SEQ + s) * DH + d] = bv;
          else
            vt[(((size_t)(b * HEADS + h)) * DH + d) * SEQ + s] = bv;
        } else {
          fout[(size_t)r * DMODEL + c] = v;
        }
      }
    }
  }
}

// ---------------- causal flash attention, 32x32 MFMA, in-register P --------
// grid: 256 blocks (xcd-colocated: bid&7 = xcd owns bh group), 512 thr =
// 8 waves = 2 teams x 4 waves. Wave owns 32 q-rows; block 128 q-rows.
// Paired q-tiles {j, 15-j} of 128 rows -> 34 kv-tiles(64) total, uniform.
// Teams split kv tiles even/odd; LDS merge per phase.
// Swapped QK^T via mfma_32x32x16: S^T col=lane&31=q, row=crow(r,hi).
// Softmax fully in registers; P->A-frag via cvt_pk_bf16 + permlane32_swap.
// permlane32_swap(a,b): a.hi <-> b.lo, so a_final=(a.lo, b.lo^), b_final=
// (a.hi_v, b.hi): swap(x[4g+0], x[4g+2]) -> x0 = word0, x2 = word2. [R9 fix]
__global__ __launch_bounds__(512, 2) void attn_fwd(
    const unsigned short* __restrict__ q, const unsigned short* __restrict__ k,
    const unsigned short* __restrict__ vt, unsigned short* __restrict__ attn)
{
  __shared__ alignas(16) unsigned short smem[32768];  // 64 KB
  // K tile (buf,team): smem + ((buf*2+team)*4096), V: +16384

  const int tid = threadIdx.x, lane = tid & 63, wave = tid >> 6;
  const int team = wave >> 2, wsub = wave & 3;
  const int l31 = lane & 31, hi = lane >> 5;

  const int bid = blockIdx.x;
  const int xcd = bid & 7, slot = bid >> 3;
  const int bh = xcd * 4 + (slot >> 3);
  const int j = slot & 7;
  const int q0a = j * 128, q0b = (15 - j) * 128;
  const int ntA = 2 * j + 2, ntB = 32 - 2 * j;

  const unsigned short* qg = q + ((size_t)bh * SEQ) * DH;
  const unsigned short* kg = k + ((size_t)bh * SEQ) * DH;
  const unsigned short* vg = vt + ((size_t)bh * DH) * SEQ;

  // staging offsets: row = tid>>3, chunk ^= row&7
  const int srow = tid >> 3;
  const int sc = (tid & 7) ^ (srow & 7);
  const int kOff = srow * DH + sc * 8;
  const int vOff = srow * SEQ + sc * 8;

  auto stage = [&](int bi, int u0, int u1, int nt) {
    const int kv0 = u0 * 64;
    const int kv1 = (u1 < nt ? u1 : 0) * 64;
    __builtin_amdgcn_global_load_lds(
        (const __attribute__((address_space(1))) void*)(kg + (size_t)kv0 * DH + kOff),
        (__attribute__((address_space(3))) void*)(&smem[(bi * 2 + 0) * 4096 + tid * 8]), 16, 0, 0);
    __builtin_amdgcn_global_load_lds(
        (const __attribute__((address_space(1))) void*)(vg + (size_t)kv0 + vOff),
        (__attribute__((address_space(3))) void*)(&smem[16384 + (bi * 2 + 0) * 4096 + tid * 8]), 16, 0, 0);
    __builtin_amdgcn_global_load_lds(
        (const __attribute__((address_space(1))) void*)(kg + (size_t)kv1 * DH + kOff),
        (__attribute__((address_space(3))) void*)(&smem[(bi * 2 + 1) * 4096 + tid * 8]), 16, 0, 0);
    __builtin_amdgcn_global_load_lds(
        (const __attribute__((address_space(1))) void*)(vg + (size_t)kv1 + vOff),
        (__attribute__((address_space(3))) void*)(&smem[16384 + (bi * 2 + 1) * 4096 + tid * 8]), 16, 0, 0);
  };

  const float CSC = 0.18033688011112042f;  // 0.125 * log2(e)
  const float THR = 44.3614195558365f;     // 8 / CSC
  const int b = bh >> 4, h = bh & 15;

  auto phase = [&](int q0, int nt) {
    const int qw = q0 + wsub * 32;
    // Q B-frags: col=l31 -> q=qw+l31, k=hi*8+i at d=ks*16+hi*8+i
    bf16x8 qf[4];
#pragma unroll
    for (int ks = 0; ks < 4; ++ks)
      qf[ks] = *(const bf16x8*)(qg + (size_t)(qw + l31) * DH + ks * 16 + hi * 8);

    f32x16 O0 = {}, O1 = {};
    float m_r = -1e30f, l_r = 0.f;

    const int nsteps = (nt + 1) >> 1;
    stage(0, 0, 1, nt);
    for (int i = 0; i < nsteps; ++i) {
      const bool pf = (i + 1 < nsteps);
      if (pf) stage((i + 1) & 1, 2 * (i + 1), 2 * (i + 1) + 1, nt);
      if (pf) { asm volatile("s_waitcnt vmcnt(4)" ::: "memory"); }
      else    { asm volatile("s_waitcnt vmcnt(0)" ::: "memory"); }
      __builtin_amdgcn_s_barrier();
      asm volatile("" ::: "memory");

      const int u = 2 * i + team;
      const int kv0 = u * 64;
      if (u < nt && kv0 <= qw + 31) {
        const int bi = i & 1;
        const char* sKb = (const char*)&smem[(bi * 2 + team) * 4096];
        const char* sVb = (const char*)&smem[16384 + (bi * 2 + team) * 4096];

        // ---- QK^T: S^T[64kv][32q], 2 kv-subtiles of 32
        f32x16 st0 = {}, st1 = {};
        __builtin_amdgcn_s_setprio(1);
#pragma unroll
        for (int ks = 0; ks < 4; ++ks) {
          const int r0 = l31, r1 = 32 + l31;
          const bf16x8 a0 = *(const bf16x8*)(sKb + r0 * 128 + (((ks * 2 + hi) ^ (r0 & 7)) * 16));
          const bf16x8 a1 = *(const bf16x8*)(sKb + r1 * 128 + (((ks * 2 + hi) ^ (r1 & 7)) * 16));
          st0 = __builtin_amdgcn_mfma_f32_32x32x16_bf16(a0, qf[ks], st0, 0, 0, 0);
          st1 = __builtin_amdgcn_mfma_f32_32x32x16_bf16(a1, qf[ks], st1, 0, 0, 0);
        }
        __builtin_amdgcn_s_setprio(0);

        // ---- mask + row max (lane owns q=qw+l31; rows crow(r,hi))
        const bool needmask = (kv0 + 63 > qw);
        const int qrow = qw + l31;
        float p[32];
        float mx = -1e30f;
#pragma unroll
        for (int t = 0; t < 2; ++t)
#pragma unroll
          for (int r = 0; r < 16; ++r) {
            float v = t ? st1[r] : st0[r];
            if (needmask) {
              const int kv = kv0 + t * 32 + (r & 3) + 8 * (r >> 2) + 4 * hi;
              v = (kv <= qrow) ? v : -1e30f;
            }
            p[t * 16 + r] = v;
            mx = fmaxf(mx, v);
          }
        mx = fmaxf(mx, __shfl_xor(mx, 32));

        // ---- defer-max (T13)
        if (!__all(mx - m_r <= THR)) {
          const float mn = fmaxf(m_r, mx);
          const float al = exp2f((m_r - mn) * CSC);
          l_r *= al;
          m_r = mn;
#pragma unroll
          for (int r = 0; r < 16; ++r) {
            const int cr = (r & 3) + 8 * (r >> 2) + 4 * hi;
            const float ac = __shfl(al, cr);
            O0[r] *= ac; O1[r] *= ac;
          }
        }

        // ---- exp + sum + pack to bf16 pairs
        const float nm = -m_r * CSC;
        float ps = 0.f;
        unsigned int x[16];
#pragma unroll
        for (int i2 = 0; i2 < 16; ++i2) {
          const float e0 = exp2f(__builtin_fmaf(p[2 * i2], CSC, nm));
          const float e1 = exp2f(__builtin_fmaf(p[2 * i2 + 1], CSC, nm));
          ps += e0 + e1;
          asm("v_cvt_pk_bf16_f32 %0, %1, %2" : "=v"(x[i2]) : "v"(e0), "v"(e1));
        }
        ps += __shfl_xor(ps, 32);
        l_r += ps;

        // ---- permlane32_swap: build A-frags (kv k-blocks of 16)
        // swap(a,b): a.hi <-> b.lo => a=(a.lo,b.lo^), b=(a.hi_v,b.hi)
        // word0 = swap-a of (x0,x2); word2 = swap-b of (x0,x2)  [R9 fix]
#pragma unroll
        for (int g = 0; g < 4; ++g) {
          asm("v_permlane32_swap_b32 %0, %1" : "+v"(x[g * 4 + 0]), "+v"(x[g * 4 + 2]));
          asm("v_permlane32_swap_b32 %0, %1" : "+v"(x[g * 4 + 1]), "+v"(x[g * 4 + 3]));
        }

        // ---- PV: O[32q][64d] += P * V ; B-frags from V^T LDS
        __builtin_amdgcn_s_setprio(1);
#pragma unroll
        for (int g = 0; g < 4; ++g) {
          uint4v pw;
          pw[0] = x[g * 4 + 0]; pw[1] = x[g * 4 + 1];
          pw[2] = x[g * 4 + 2]; pw[3] = x[g * 4 + 3];
          const bf16x8 pa = __builtin_bit_cast(bf16x8, pw);
          const int vr0 = l31, vr1 = 32 + l31;
          const bf16x8 b0 = *(const bf16x8*)(sVb + vr0 * 128 + (((g * 2 + hi) ^ (vr0 & 7)) * 16));
          const bf16x8 b1 = *(const bf16x8*)(sVb + vr1 * 128 + (((g * 2 + hi) ^ (vr1 & 7)) * 16));
          O0 = __builtin_amdgcn_mfma_f32_32x32x16_bf16(pa, b0, O0, 0, 0, 0);
          O1 = __builtin_amdgcn_mfma_f32_32x32x16_bf16(pa, b1, O1, 0, 0, 0);
        }
        __builtin_amdgcn_s_setprio(0);
      }
      __builtin_amdgcn_s_barrier();
      asm volatile("" ::: "memory");
    }

    // ---- team merge + output (scratch aliases K/V region)
    float* F = (float*)&smem[0];
    __syncthreads();
    if (team == 1) {
      F[wsub * 64 + lane] = m_r;
      F[256 + wsub * 64 + lane] = l_r;
#pragma unroll
      for (int r = 0; r < 16; ++r) {
        F[512 + r * 256 + wsub * 64 + lane] = O0[r];
        F[512 + (16 + r) * 256 + wsub * 64 + lane] = O1[r];
      }
    }
    __syncthreads();
    if (team == 0) {
      const float m1 = F[wsub * 64 + lane], l1 = F[256 + wsub * 64 + lane];
      const float ms = fmaxf(m_r, m1);
      const float a0 = exp2f((m_r - ms) * CSC);
      const float a1 = exp2f((m1 - ms) * CSC);
      const float inv = 1.0f / (l_r * a0 + l1 * a1);
#pragma unroll
      for (int r = 0; r < 16; ++r) {
        const int cr = (r & 3) + 8 * (r >> 2) + 4 * hi;
        const float c0 = __shfl(a0, cr), c1 = __shfl(a1, cr), iv = __shfl(inv, cr);
        const size_t ro = ((size_t)(b * SEQ + q0 + wsub * 32 + cr)) * DMODEL + h * DH + l31;
        const float o0 = O0[r] * c0 + F[512 + r * 256 + wsub * 64 + lane] * c1;
        const float o1 = O1[r] * c0 + F[512 + (16 + r) * 256 + wsub * 64 + lane] * c1;
        attn[ro] = f2bf(o0 * iv);
        attn[ro + 32] = f2bf(o1 * iv);
      }
    }
    __syncthreads();
  };

  phase(q0a, ntA);
  phase(q0b, ntB);
}

// ---------------------------------------------------------------------------
extern "C" void kernel_launch(void* const* d_in, const int* in_sizes, int n_in,
                              void* d_out, int out_size, void* d_ws, size_t ws_size,
                              hipStream_t stream) {
  const float* x  = (const float*)d_in[0];
  // d_in[1] = causal mask (tril) — structure known, not read
  const float* Wq = (const float*)d_in[2];
  const float* Wk = (const float*)d_in[3];
  const float* Wv = (const float*)d_in[4];
  const float* Wo = (const float*)d_in[5];
  float* out = (float*)d_out;

  unsigned short* ws = (unsigned short*)d_ws;
  const size_t MEL = (size_t)1024 * 1024;
  unsigned short* xb   = ws;            // 4M elems
  unsigned short* wqkv = xb + 4 * MEL;  // 3M (Wq|Wk|Wv rows)
  unsigned short* wo   = wqkv + 3 * MEL;// 1M
  unsigned short* qb   = wo + MEL;      // 4M  [bh][s][64]
  unsigned short* kb   = qb + 4 * MEL;  // 4M  [bh][s][64]
  unsigned short* vtb  = kb + 4 * MEL;  // 4M  [bh][64][s]
  unsigned short* attn = vtb + 4 * MEL; // 4M  [b*s][1024]

  cvt8<<<2048, 256, 0, stream>>>(x, xb, 524288);
  cvtW<<<dim3(512, 4), 256, 0, stream>>>(Wq, Wk, Wv, Wo, wqkv);

  // QKV projection: 24 x 32 = 768 blocks (3/CU resident, uniform)
  gemm_p3<0><<<768, 256, 0, stream>>>(xb, wqkv, 24, qb, kb, vtb, nullptr);

  // attention: 256 blocks, xcd-colocated bh, paired 128-row q-tiles
  attn_fwd<<<256, 512, 0, stream>>>(qb, kb, vtb, attn);

  // output projection: 8 x 32 = 256 blocks
  gemm_p3<1><<<256, 256, 0, stream>>>(attn, wo, 8, nullptr, nullptr, nullptr, out);
}